// Round 8
// baseline (669.515 us; speedup 1.0000x reference)
//
#include <hip/hip_runtime.h>

#define BATCH 256
#define TLEN  512
#define DIN   64
#define HID   128
#define NOUT  40

typedef _Float16 f16x8 __attribute__((ext_vector_type(8)));
typedef _Float16 f16x4 __attribute__((ext_vector_type(4)));
typedef float    f32x4 __attribute__((ext_vector_type(4)));

#define MFMA16(a, b, c) __builtin_amdgcn_mfma_f32_16x16x32_f16((a), (b), (c), 0, 0, 0)

// MFMA with B read DIRECTLY from AGPR (no accvgpr_read copies).
static __device__ __forceinline__ f32x4 mfma_a(f16x8 a, f16x8 b, f32x4 c) {
    f32x4 d;
    asm("v_mfma_f32_16x16x32_f16 %0, %1, %2, %3"
        : "=&v"(d)
        : "v"(a), "a"(b), "v"(c));
    return d;
}

// LDS-visibility barrier only: no vmcnt drain.
#define BARRIER() do {                                      \
    asm volatile("s_waitcnt lgkmcnt(0)" ::: "memory");      \
    __builtin_amdgcn_s_barrier();                           \
} while (0)

static __device__ __forceinline__ f16x8 pack8(float4 a, float4 b) {
    f16x8 v;
    v[0] = (_Float16)a.x; v[1] = (_Float16)a.y; v[2] = (_Float16)a.z; v[3] = (_Float16)a.w;
    v[4] = (_Float16)b.x; v[5] = (_Float16)b.y; v[6] = (_Float16)b.z; v[7] = (_Float16)b.w;
    return v;
}
static __device__ __forceinline__ float sig_(float x) {
    return __builtin_amdgcn_rcpf(1.0f + __expf(-x));
}
static __device__ __forceinline__ float tanh_(float x) {
    return fmaf(-2.0f, __builtin_amdgcn_rcpf(__expf(2.0f * x) + 1.0f), 1.0f);
}

// Weight fragment loader; uses kernel-local `kg`. k = kt*32 + kg*8 + j.
#define LD8(base, g, K, kt) pack8(*(const float4*)((base) + (size_t)(g) * (K) + (kt) * 32 + kg * 8), \
                                  *(const float4*)((base) + (size_t)(g) * (K) + (kt) * 32 + kg * 8 + 4))

// ===================== Layer 0 =====================
// 256 blocks x 512 thr (8 waves). Wave w owns hid [w*16,w*16+16), all 4 gates
// (in-wave ACT). Weights: AGPR-resident, consumed in place by asm MFMA; the
// final chain fragment (Wh*3) stays in VGPR + builtin MFMA for hazard safety.
__global__ void __attribute__((amdgpu_flat_work_group_size(512, 512), amdgpu_waves_per_eu(2, 2)))
lstm_l0(const float* __restrict__ x,
        const float* __restrict__ Wih, const float* __restrict__ Whh,
        const float* __restrict__ bih, const float* __restrict__ bhh,
        float* __restrict__ hstate, float* __restrict__ cstate,
        _Float16* __restrict__ y0, int t0, int t1)
{
    const int b    = blockIdx.x;
    const int tid  = threadIdx.x;
    const int lane = tid & 63, wave = tid >> 6;
    const int col  = lane & 15, kg = lane >> 4;
    const int hid  = wave * 16 + col;

    __shared__ __align__(16) _Float16 x_lds[2][DIN];
    __shared__ __align__(16) _Float16 h_lds[2][HID];

    // ---- weight fragments ----
    f16x8 Wx00 = LD8(Wih, 0 * HID + hid, DIN, 0), Wx01 = LD8(Wih, 0 * HID + hid, DIN, 1);
    f16x8 Wx10 = LD8(Wih, 1 * HID + hid, DIN, 0), Wx11 = LD8(Wih, 1 * HID + hid, DIN, 1);
    f16x8 Wx20 = LD8(Wih, 2 * HID + hid, DIN, 0), Wx21 = LD8(Wih, 2 * HID + hid, DIN, 1);
    f16x8 Wx30 = LD8(Wih, 3 * HID + hid, DIN, 0), Wx31 = LD8(Wih, 3 * HID + hid, DIN, 1);
    f16x8 Wh00 = LD8(Whh, 0 * HID + hid, HID, 0), Wh01 = LD8(Whh, 0 * HID + hid, HID, 1);
    f16x8 Wh02 = LD8(Whh, 0 * HID + hid, HID, 2), Wh03 = LD8(Whh, 0 * HID + hid, HID, 3);
    f16x8 Wh10 = LD8(Whh, 1 * HID + hid, HID, 0), Wh11 = LD8(Whh, 1 * HID + hid, HID, 1);
    f16x8 Wh12 = LD8(Whh, 1 * HID + hid, HID, 2), Wh13 = LD8(Whh, 1 * HID + hid, HID, 3);
    f16x8 Wh20 = LD8(Whh, 2 * HID + hid, HID, 0), Wh21 = LD8(Whh, 2 * HID + hid, HID, 1);
    f16x8 Wh22 = LD8(Whh, 2 * HID + hid, HID, 2), Wh23 = LD8(Whh, 2 * HID + hid, HID, 3);
    f16x8 Wh30 = LD8(Whh, 3 * HID + hid, HID, 0), Wh31 = LD8(Whh, 3 * HID + hid, HID, 1);
    f16x8 Wh32 = LD8(Whh, 3 * HID + hid, HID, 2), Wh33 = LD8(Whh, 3 * HID + hid, HID, 3);
    // Pin all but the chain-final fragments (Wh03/13/23/33 stay VGPR).
    asm("" : "+a"(Wx00), "+a"(Wx01), "+a"(Wx10), "+a"(Wx11),
             "+a"(Wx20), "+a"(Wx21), "+a"(Wx30), "+a"(Wx31));
    asm("" : "+a"(Wh00), "+a"(Wh01), "+a"(Wh02),
             "+a"(Wh10), "+a"(Wh11), "+a"(Wh12));
    asm("" : "+a"(Wh20), "+a"(Wh21), "+a"(Wh22),
             "+a"(Wh30), "+a"(Wh31), "+a"(Wh32));

    const float bs0 = bih[0 * HID + hid] + bhh[0 * HID + hid];
    const float bs1 = bih[1 * HID + hid] + bhh[1 * HID + hid];
    const float bs2 = bih[2 * HID + hid] + bhh[2 * HID + hid];
    const float bs3 = bih[3 * HID + hid] + bhh[3 * HID + hid];
    const f32x4 z4 = {0.f, 0.f, 0.f, 0.f};

    float cc = cstate[(size_t)b * HID + hid];
    float hv = hstate[(size_t)b * HID + hid];
    if (kg == 0) h_lds[0][hid] = (_Float16)hv;

    // x loaders: wave 7 lanes 0..15, coalesced float4, distance-2 prefetch
    const float4* xrow = (const float4*)(x + (size_t)b * TLEN * DIN);
    const int lk = tid - 448;
    const bool ldr = ((unsigned)lk < 16u);
    float4 xpfA = make_float4(0, 0, 0, 0), xpfB = xpfA;
    if (ldr) {
        float4 v = xrow[(size_t)t0 * (DIN / 4) + lk];
        f16x4 pw; pw[0] = (_Float16)v.x; pw[1] = (_Float16)v.y;
        pw[2] = (_Float16)v.z; pw[3] = (_Float16)v.w;
        *(f16x4*)&x_lds[0][lk * 4] = pw;
        int ta = t0 + 1 < TLEN ? t0 + 1 : TLEN - 1;
        int tb = t0 + 2 < TLEN ? t0 + 2 : TLEN - 1;
        xpfA = xrow[(size_t)ta * (DIN / 4) + lk];
        xpfB = xrow[(size_t)tb * (DIN / 4) + lk];
    }
    BARRIER();

#define L0_STEP(T, P, XPF) do {                                                  \
    if (ldr) {                                                                   \
        f16x4 pw; pw[0] = (_Float16)XPF.x; pw[1] = (_Float16)XPF.y;              \
        pw[2] = (_Float16)XPF.z; pw[3] = (_Float16)XPF.w;                        \
        *(f16x4*)&x_lds[(P) ^ 1][lk * 4] = pw;                                   \
        int tn = (T) + 3; if (tn > TLEN - 1) tn = TLEN - 1;                      \
        XPF = xrow[(size_t)tn * (DIN / 4) + lk];                                 \
    }                                                                            \
    f16x8 xa0 = *(const f16x8*)&x_lds[P][kg * 8];                                \
    f16x8 xa1 = *(const f16x8*)&x_lds[P][32 + kg * 8];                           \
    f16x8 ha0 = *(const f16x8*)&h_lds[P][kg * 8];                                \
    f16x8 ha1 = *(const f16x8*)&h_lds[P][32 + kg * 8];                           \
    f16x8 ha2 = *(const f16x8*)&h_lds[P][64 + kg * 8];                           \
    f16x8 ha3 = *(const f16x8*)&h_lds[P][96 + kg * 8];                           \
    f32x4 a0 = mfma_a(xa0, Wx00, z4);                                            \
    f32x4 a1 = mfma_a(xa0, Wx10, z4);                                            \
    f32x4 a2 = mfma_a(xa0, Wx20, z4);                                            \
    f32x4 a3 = mfma_a(xa0, Wx30, z4);                                            \
    a0 = mfma_a(xa1, Wx01, a0); a1 = mfma_a(xa1, Wx11, a1);                      \
    a2 = mfma_a(xa1, Wx21, a2); a3 = mfma_a(xa1, Wx31, a3);                      \
    a0 = mfma_a(ha0, Wh00, a0); a1 = mfma_a(ha0, Wh10, a1);                      \
    a2 = mfma_a(ha0, Wh20, a2); a3 = mfma_a(ha0, Wh30, a3);                      \
    a0 = mfma_a(ha1, Wh01, a0); a1 = mfma_a(ha1, Wh11, a1);                      \
    a2 = mfma_a(ha1, Wh21, a2); a3 = mfma_a(ha1, Wh31, a3);                      \
    a0 = mfma_a(ha2, Wh02, a0); a1 = mfma_a(ha2, Wh12, a1);                      \
    a2 = mfma_a(ha2, Wh22, a2); a3 = mfma_a(ha2, Wh32, a3);                      \
    a0 = MFMA16(ha3, Wh03, a0); a1 = MFMA16(ha3, Wh13, a1);                      \
    a2 = MFMA16(ha3, Wh23, a2); a3 = MFMA16(ha3, Wh33, a3);                      \
    float iv = sig_(a0[0] + bs0), fv = sig_(a1[0] + bs1);                        \
    float gv = tanh_(a2[0] + bs2), ov = sig_(a3[0] + bs3);                       \
    cc = fmaf(fv, cc, iv * gv);                                                  \
    hv = ov * tanh_(cc);                                                         \
    _Float16 hh = (_Float16)hv;                                                  \
    if (kg == 0) {                                                               \
        h_lds[(P) ^ 1][hid] = hh;                                                \
        y0[((size_t)((T) - t0) * BATCH + b) * HID + hid] = hh;                   \
    }                                                                            \
    BARRIER();                                                                   \
} while (0)

    const int nt = t1 - t0;                            // even by construction
    for (int s = 0; s + 1 < nt; s += 2) {
        L0_STEP(t0 + s,     0, xpfA);
        L0_STEP(t0 + s + 1, 1, xpfB);
    }
#undef L0_STEP

    if (kg == 0) {
        cstate[(size_t)b * HID + hid] = cc;
        hstate[(size_t)b * HID + hid] = hv;
    }
}

// ===================== Layer 1 =====================
__global__ void __attribute__((amdgpu_flat_work_group_size(512, 512), amdgpu_waves_per_eu(2, 2)))
lstm_l1(const _Float16* __restrict__ y0in,
        const float* __restrict__ Wih, const float* __restrict__ Whh,
        const float* __restrict__ bih, const float* __restrict__ bhh,
        float* __restrict__ hstate, float* __restrict__ cstate,
        int t0, int t1)
{
    const int b    = blockIdx.x;
    const int tid  = threadIdx.x;
    const int lane = tid & 63, wave = tid >> 6;
    const int col  = lane & 15, kg = lane >> 4;
    const int hid  = wave * 16 + col;

    __shared__ __align__(16) _Float16 y_lds[2][HID];
    __shared__ __align__(16) _Float16 h_lds[2][HID];

    f16x8 Wy00 = LD8(Wih, 0 * HID + hid, HID, 0), Wy01 = LD8(Wih, 0 * HID + hid, HID, 1);
    f16x8 Wy02 = LD8(Wih, 0 * HID + hid, HID, 2), Wy03 = LD8(Wih, 0 * HID + hid, HID, 3);
    f16x8 Wy10 = LD8(Wih, 1 * HID + hid, HID, 0), Wy11 = LD8(Wih, 1 * HID + hid, HID, 1);
    f16x8 Wy12 = LD8(Wih, 1 * HID + hid, HID, 2), Wy13 = LD8(Wih, 1 * HID + hid, HID, 3);
    f16x8 Wy20 = LD8(Wih, 2 * HID + hid, HID, 0), Wy21 = LD8(Wih, 2 * HID + hid, HID, 1);
    f16x8 Wy22 = LD8(Wih, 2 * HID + hid, HID, 2), Wy23 = LD8(Wih, 2 * HID + hid, HID, 3);
    f16x8 Wy30 = LD8(Wih, 3 * HID + hid, HID, 0), Wy31 = LD8(Wih, 3 * HID + hid, HID, 1);
    f16x8 Wy32 = LD8(Wih, 3 * HID + hid, HID, 2), Wy33 = LD8(Wih, 3 * HID + hid, HID, 3);
    f16x8 Wh00 = LD8(Whh, 0 * HID + hid, HID, 0), Wh01 = LD8(Whh, 0 * HID + hid, HID, 1);
    f16x8 Wh02 = LD8(Whh, 0 * HID + hid, HID, 2), Wh03 = LD8(Whh, 0 * HID + hid, HID, 3);
    f16x8 Wh10 = LD8(Whh, 1 * HID + hid, HID, 0), Wh11 = LD8(Whh, 1 * HID + hid, HID, 1);
    f16x8 Wh12 = LD8(Whh, 1 * HID + hid, HID, 2), Wh13 = LD8(Whh, 1 * HID + hid, HID, 3);
    f16x8 Wh20 = LD8(Whh, 2 * HID + hid, HID, 0), Wh21 = LD8(Whh, 2 * HID + hid, HID, 1);
    f16x8 Wh22 = LD8(Whh, 2 * HID + hid, HID, 2), Wh23 = LD8(Whh, 2 * HID + hid, HID, 3);
    f16x8 Wh30 = LD8(Whh, 3 * HID + hid, HID, 0), Wh31 = LD8(Whh, 3 * HID + hid, HID, 1);
    f16x8 Wh32 = LD8(Whh, 3 * HID + hid, HID, 2), Wh33 = LD8(Whh, 3 * HID + hid, HID, 3);
    asm("" : "+a"(Wy00), "+a"(Wy01), "+a"(Wy02), "+a"(Wy03),
             "+a"(Wy10), "+a"(Wy11), "+a"(Wy12), "+a"(Wy13));
    asm("" : "+a"(Wy20), "+a"(Wy21), "+a"(Wy22), "+a"(Wy23),
             "+a"(Wy30), "+a"(Wy31), "+a"(Wy32), "+a"(Wy33));
    asm("" : "+a"(Wh00), "+a"(Wh01), "+a"(Wh02),
             "+a"(Wh10), "+a"(Wh11), "+a"(Wh12));
    asm("" : "+a"(Wh20), "+a"(Wh21), "+a"(Wh22),
             "+a"(Wh30), "+a"(Wh31), "+a"(Wh32));

    const float bs0 = bih[0 * HID + hid] + bhh[0 * HID + hid];
    const float bs1 = bih[1 * HID + hid] + bhh[1 * HID + hid];
    const float bs2 = bih[2 * HID + hid] + bhh[2 * HID + hid];
    const float bs3 = bih[3 * HID + hid] + bhh[3 * HID + hid];
    const f32x4 z4 = {0.f, 0.f, 0.f, 0.f};

    float cc = cstate[(size_t)b * HID + hid];
    float hv = hstate[(size_t)b * HID + hid];
    if (kg == 0) h_lds[0][hid] = (_Float16)hv;

    const uint4* yrow = (const uint4*)(y0in);
    const int lk = tid - 448;
    const bool ldr = ((unsigned)lk < 16u);
    const int nt = t1 - t0;
    uint4 ypfA = make_uint4(0, 0, 0, 0), ypfB = ypfA;
    if (ldr) {
        *(uint4*)&y_lds[0][lk * 8] = yrow[((size_t)0 * BATCH + b) * (HID / 8) + lk];
        int ra = 1 < nt - 1 ? 1 : nt - 1;
        int rb = 2 < nt - 1 ? 2 : nt - 1;
        ypfA = yrow[((size_t)ra * BATCH + b) * (HID / 8) + lk];
        ypfB = yrow[((size_t)rb * BATCH + b) * (HID / 8) + lk];
    }
    BARRIER();

#define L1_STEP(REL, P, YPF) do {                                                \
    if (ldr) {                                                                   \
        *(uint4*)&y_lds[(P) ^ 1][lk * 8] = YPF;                                  \
        int rn = (REL) + 3; if (rn > nt - 1) rn = nt - 1;                        \
        YPF = yrow[((size_t)rn * BATCH + b) * (HID / 8) + lk];                   \
    }                                                                            \
    f16x8 ya0 = *(const f16x8*)&y_lds[P][kg * 8];                                \
    f16x8 ya1 = *(const f16x8*)&y_lds[P][32 + kg * 8];                           \
    f16x8 ya2 = *(const f16x8*)&y_lds[P][64 + kg * 8];                           \
    f16x8 ya3 = *(const f16x8*)&y_lds[P][96 + kg * 8];                           \
    f16x8 ha0 = *(const f16x8*)&h_lds[P][kg * 8];                                \
    f16x8 ha1 = *(const f16x8*)&h_lds[P][32 + kg * 8];                           \
    f16x8 ha2 = *(const f16x8*)&h_lds[P][64 + kg * 8];                           \
    f16x8 ha3 = *(const f16x8*)&h_lds[P][96 + kg * 8];                           \
    f32x4 a0 = mfma_a(ya0, Wy00, z4);                                            \
    f32x4 a1 = mfma_a(ya0, Wy10, z4);                                            \
    f32x4 a2 = mfma_a(ya0, Wy20, z4);                                            \
    f32x4 a3 = mfma_a(ya0, Wy30, z4);                                            \
    a0 = mfma_a(ya1, Wy01, a0); a1 = mfma_a(ya1, Wy11, a1);                      \
    a2 = mfma_a(ya1, Wy21, a2); a3 = mfma_a(ya1, Wy31, a3);                      \
    a0 = mfma_a(ya2, Wy02, a0); a1 = mfma_a(ya2, Wy12, a1);                      \
    a2 = mfma_a(ya2, Wy22, a2); a3 = mfma_a(ya2, Wy32, a3);                      \
    a0 = mfma_a(ya3, Wy03, a0); a1 = mfma_a(ya3, Wy13, a1);                      \
    a2 = mfma_a(ya3, Wy23, a2); a3 = mfma_a(ya3, Wy33, a3);                      \
    a0 = mfma_a(ha0, Wh00, a0); a1 = mfma_a(ha0, Wh10, a1);                      \
    a2 = mfma_a(ha0, Wh20, a2); a3 = mfma_a(ha0, Wh30, a3);                      \
    a0 = mfma_a(ha1, Wh01, a0); a1 = mfma_a(ha1, Wh11, a1);                      \
    a2 = mfma_a(ha1, Wh21, a2); a3 = mfma_a(ha1, Wh31, a3);                      \
    a0 = mfma_a(ha2, Wh02, a0); a1 = mfma_a(ha2, Wh12, a1);                      \
    a2 = mfma_a(ha2, Wh22, a2); a3 = mfma_a(ha2, Wh32, a3);                      \
    a0 = MFMA16(ha3, Wh03, a0); a1 = MFMA16(ha3, Wh13, a1);                      \
    a2 = MFMA16(ha3, Wh23, a2); a3 = MFMA16(ha3, Wh33, a3);                      \
    float iv = sig_(a0[0] + bs0), fv = sig_(a1[0] + bs1);                        \
    float gv = tanh_(a2[0] + bs2), ov = sig_(a3[0] + bs3);                       \
    cc = fmaf(fv, cc, iv * gv);                                                  \
    hv = ov * tanh_(cc);                                                         \
    if (kg == 0) h_lds[(P) ^ 1][hid] = (_Float16)hv;                             \
    BARRIER();                                                                   \
} while (0)

    for (int s = 0; s + 1 < nt; s += 2) {
        L1_STEP(s,     0, ypfA);
        L1_STEP(s + 1, 1, ypfB);
    }
#undef L1_STEP

    if (kg == 0) {
        cstate[(size_t)b * HID + hid] = cc;
        hstate[(size_t)b * HID + hid] = hv;   // final h1 (fc reads this)
    }
}

// ===================== Final FC =====================
__global__ __launch_bounds__(128) void fc_kernel(
    const float* __restrict__ h1, const float* __restrict__ Wfc,
    const float* __restrict__ bfc, float* __restrict__ out)
{
    const int b = blockIdx.x;
    const int o = threadIdx.x;
    __shared__ float hs[HID];
    hs[o] = h1[(size_t)b * HID + o];
    __syncthreads();
    if (o < NOUT) {
        const float4* w  = reinterpret_cast<const float4*>(Wfc + (size_t)o * HID);
        const float4* hv = reinterpret_cast<const float4*>(hs);
        float acc = bfc[o];
        #pragma unroll
        for (int q = 0; q < HID / 4; ++q) {
            float4 wv = w[q]; float4 h4 = hv[q];
            acc = fmaf(wv.x, h4.x, fmaf(wv.y, h4.y, fmaf(wv.z, h4.z, fmaf(wv.w, h4.w, acc))));
        }
        out[(size_t)b * NOUT + o] = acc;
    }
}

extern "C" void kernel_launch(void* const* d_in, const int* in_sizes, int n_in,
                              void* d_out, int out_size, void* d_ws, size_t ws_size,
                              hipStream_t stream) {
    const float* x    = (const float*)d_in[0];
    const float* Wih0 = (const float*)d_in[1];
    const float* Whh0 = (const float*)d_in[2];
    const float* bih0 = (const float*)d_in[3];
    const float* bhh0 = (const float*)d_in[4];
    const float* Wih1 = (const float*)d_in[5];
    const float* Whh1 = (const float*)d_in[6];
    const float* bih1 = (const float*)d_in[7];
    const float* bhh1 = (const float*)d_in[8];
    const float* Wfc  = (const float*)d_in[9];
    const float* bfc  = (const float*)d_in[10];
    float* out = (float*)d_out;

    // ws: hst0 | cst0 | hst1 | cst1 (f32, 128KB each) then y0 slab (f16)
    float* hst0 = (float*)d_ws;
    float* cst0 = hst0 + BATCH * HID;
    float* hst1 = cst0 + BATCH * HID;
    float* cst1 = hst1 + BATCH * HID;
    _Float16* y0 = (_Float16*)(cst1 + BATCH * HID);

    const size_t stateBytes = (size_t)4 * BATCH * HID * sizeof(float);   // 512 KB
    size_t avail = ws_size > stateBytes ? ws_size - stateBytes : 0;
    int Tc = (int)(avail / ((size_t)BATCH * HID * 2));
    if (Tc > TLEN) Tc = TLEN;
    Tc &= ~1;
    if (Tc < 2) Tc = 2;

    hipMemsetAsync(d_ws, 0, stateBytes, stream);

    for (int t0 = 0; t0 < TLEN; t0 += Tc) {
        int t1 = t0 + Tc; if (t1 > TLEN) t1 = TLEN;
        lstm_l0<<<BATCH, 512, 0, stream>>>(x, Wih0, Whh0, bih0, bhh0, hst0, cst0, y0, t0, t1);
        lstm_l1<<<BATCH, 512, 0, stream>>>(y0, Wih1, Whh1, bih1, bhh1, hst1, cst1, t0, t1);
    }
    fc_kernel<<<BATCH, 128, 0, stream>>>(hst1, Wfc, bfc, out);
}

// Round 9
// 578.339 us; speedup vs baseline: 1.1577x; 1.1577x over previous
//
#include <hip/hip_runtime.h>

#define BATCH 256
#define TLEN  512
#define DIN   64
#define HID   128
#define NOUT  40
#define SC    16   // sub-chunk: input projections precomputed 16 steps at a time

typedef _Float16 f16x8 __attribute__((ext_vector_type(8)));
typedef float    f32x4 __attribute__((ext_vector_type(4)));

#define MFMA16(a, b, c) __builtin_amdgcn_mfma_f32_16x16x32_f16((a), (b), (c), 0, 0, 0)

// LDS-visibility barrier only: no vmcnt drain.
#define BARRIER() do {                                      \
    asm volatile("s_waitcnt lgkmcnt(0)" ::: "memory");      \
    __builtin_amdgcn_s_barrier();                           \
} while (0)

static __device__ __forceinline__ f16x8 pack8(float4 a, float4 b) {
    f16x8 v;
    v[0] = (_Float16)a.x; v[1] = (_Float16)a.y; v[2] = (_Float16)a.z; v[3] = (_Float16)a.w;
    v[4] = (_Float16)b.x; v[5] = (_Float16)b.y; v[6] = (_Float16)b.z; v[7] = (_Float16)b.w;
    return v;
}
static __device__ __forceinline__ float sig_(float x) {
    return __builtin_amdgcn_rcpf(1.0f + __expf(-x));
}
static __device__ __forceinline__ float tanh_(float x) {
    return fmaf(-2.0f, __builtin_amdgcn_rcpf(__expf(2.0f * x) + 1.0f), 1.0f);
}
static __device__ __forceinline__ f32x4 splat4(float v) { return (f32x4){v, v, v, v}; }

// Weight fragment loader; uses kernel-local `kg`. k = kt*32 + kg*8 + j.
#define LD8(base, g, K, kt) pack8(*(const float4*)((base) + (size_t)(g) * (K) + (kt) * 32 + kg * 8), \
                                  *(const float4*)((base) + (size_t)(g) * (K) + (kt) * 32 + kg * 8 + 4))

// Steady-state recurrent step: 16 h-MFMAs, C-init from precomputed input acc.
// Uses kernel-locals: xacc, h_lds, hid, kg, cc, hv, Wh00..Wh33.
#define H_STEP_CORE(SL, P)                                                      \
    f32x4 xi = *(const f32x4*)&xacc[((SL) * HID + hid) * 4];                    \
    const _Float16* hb = &h_lds[P][0];                                          \
    f16x8 h0 = *(const f16x8*)(hb + kg * 8);                                    \
    f16x8 h1 = *(const f16x8*)(hb + 32 + kg * 8);                               \
    f16x8 h2 = *(const f16x8*)(hb + 64 + kg * 8);                               \
    f16x8 h3 = *(const f16x8*)(hb + 96 + kg * 8);                               \
    f32x4 a0 = MFMA16(h0, Wh00, xi);                                            \
    f32x4 a1 = MFMA16(h0, Wh10, splat4(xi[1]));                                 \
    f32x4 a2 = MFMA16(h0, Wh20, splat4(xi[2]));                                 \
    f32x4 a3 = MFMA16(h0, Wh30, splat4(xi[3]));                                 \
    a0 = MFMA16(h1, Wh01, a0); a1 = MFMA16(h1, Wh11, a1);                       \
    a2 = MFMA16(h1, Wh21, a2); a3 = MFMA16(h1, Wh31, a3);                       \
    a0 = MFMA16(h2, Wh02, a0); a1 = MFMA16(h2, Wh12, a1);                       \
    a2 = MFMA16(h2, Wh22, a2); a3 = MFMA16(h2, Wh32, a3);                       \
    a0 = MFMA16(h3, Wh03, a0); a1 = MFMA16(h3, Wh13, a1);                       \
    a2 = MFMA16(h3, Wh23, a2); a3 = MFMA16(h3, Wh33, a3);                       \
    float iv = sig_(a0[0]), fv = sig_(a1[0]);                                   \
    float gv = tanh_(a2[0]), ov = sig_(a3[0]);                                  \
    cc = fmaf(fv, cc, iv * gv);                                                 \
    hv = ov * tanh_(cc);

// ===================== Layer 0 =====================
// 256 blocks (one batch) x 512 thr (8 waves). Wave w owns hid [w*16,w*16+16).
// Per SC steps: GEMM phase computes xacc[t][hid][i,f,g,o] = bias + x_t·Wx with
// M=16 (timesteps as A-rows). Steady step: 16 h-MFMAs only, C-init from xacc.
__global__ void __attribute__((amdgpu_flat_work_group_size(512, 512), amdgpu_waves_per_eu(2, 2)))
lstm_l0(const float* __restrict__ x,
        const float* __restrict__ Wih, const float* __restrict__ Whh,
        const float* __restrict__ bih, const float* __restrict__ bhh,
        float* __restrict__ hstate, float* __restrict__ cstate,
        _Float16* __restrict__ y0, int t0, int t1)
{
    const int b    = blockIdx.x;
    const int tid  = threadIdx.x;
    const int lane = tid & 63;
    const int wave = tid >> 6;
    const int col  = lane & 15, kg = lane >> 4;
    const int hid  = wave * 16 + col;

    __shared__ __align__(16) float    xacc[SC * HID * 4];   // 32 KB: [(tl*128+hid)*4 + n]
    __shared__ __align__(16) _Float16 h_lds[2][HID];

    // ---- weight fragments (AGPR-pinned) ----
    f16x8 Wx00 = LD8(Wih, 0 * HID + hid, DIN, 0), Wx01 = LD8(Wih, 0 * HID + hid, DIN, 1);
    f16x8 Wx10 = LD8(Wih, 1 * HID + hid, DIN, 0), Wx11 = LD8(Wih, 1 * HID + hid, DIN, 1);
    f16x8 Wx20 = LD8(Wih, 2 * HID + hid, DIN, 0), Wx21 = LD8(Wih, 2 * HID + hid, DIN, 1);
    f16x8 Wx30 = LD8(Wih, 3 * HID + hid, DIN, 0), Wx31 = LD8(Wih, 3 * HID + hid, DIN, 1);
    f16x8 Wh00 = LD8(Whh, 0 * HID + hid, HID, 0), Wh01 = LD8(Whh, 0 * HID + hid, HID, 1);
    f16x8 Wh02 = LD8(Whh, 0 * HID + hid, HID, 2), Wh03 = LD8(Whh, 0 * HID + hid, HID, 3);
    f16x8 Wh10 = LD8(Whh, 1 * HID + hid, HID, 0), Wh11 = LD8(Whh, 1 * HID + hid, HID, 1);
    f16x8 Wh12 = LD8(Whh, 1 * HID + hid, HID, 2), Wh13 = LD8(Whh, 1 * HID + hid, HID, 3);
    f16x8 Wh20 = LD8(Whh, 2 * HID + hid, HID, 0), Wh21 = LD8(Whh, 2 * HID + hid, HID, 1);
    f16x8 Wh22 = LD8(Whh, 2 * HID + hid, HID, 2), Wh23 = LD8(Whh, 2 * HID + hid, HID, 3);
    f16x8 Wh30 = LD8(Whh, 3 * HID + hid, HID, 0), Wh31 = LD8(Whh, 3 * HID + hid, HID, 1);
    f16x8 Wh32 = LD8(Whh, 3 * HID + hid, HID, 2), Wh33 = LD8(Whh, 3 * HID + hid, HID, 3);
    asm("" : "+a"(Wx00), "+a"(Wx01), "+a"(Wx10), "+a"(Wx11),
             "+a"(Wx20), "+a"(Wx21), "+a"(Wx30), "+a"(Wx31));
    asm("" : "+a"(Wh00), "+a"(Wh01), "+a"(Wh02), "+a"(Wh03),
             "+a"(Wh10), "+a"(Wh11), "+a"(Wh12), "+a"(Wh13));
    asm("" : "+a"(Wh20), "+a"(Wh21), "+a"(Wh22), "+a"(Wh23),
             "+a"(Wh30), "+a"(Wh31), "+a"(Wh32), "+a"(Wh33));

    const float bs0 = bih[0 * HID + hid] + bhh[0 * HID + hid];
    const float bs1 = bih[1 * HID + hid] + bhh[1 * HID + hid];
    const float bs2 = bih[2 * HID + hid] + bhh[2 * HID + hid];
    const float bs3 = bih[3 * HID + hid] + bhh[3 * HID + hid];

    float cc = cstate[(size_t)b * HID + hid];
    float hv = hstate[(size_t)b * HID + hid];
    if (kg == 0) h_lds[0][hid] = (_Float16)hv;

    // GEMM A-load base: lane reads x[b][t0+sc+col][kg*8 + j] (row = timestep = col)
    const float* xA = x + (size_t)b * TLEN * DIN + (size_t)col * DIN + kg * 8;
    _Float16* y0p = y0 + (size_t)b * HID + hid;

    const int nt = t1 - t0;                       // multiple of SC by construction
    for (int sc = 0; sc < nt; sc += SC) {
        // ---- GEMM phase: xacc[tl][hid][n] = bias_n + x[t0+sc+tl]·Wx_n ----
        {
            const float* pa = xA + (size_t)(t0 + sc) * DIN;
            f16x8 A0 = pack8(*(const float4*)pa,        *(const float4*)(pa + 4));
            f16x8 A1 = pack8(*(const float4*)(pa + 32), *(const float4*)(pa + 36));
            f32x4 g0 = splat4(bs0), g1 = splat4(bs1), g2 = splat4(bs2), g3 = splat4(bs3);
            g0 = MFMA16(A0, Wx00, g0); g1 = MFMA16(A0, Wx10, g1);
            g2 = MFMA16(A0, Wx20, g2); g3 = MFMA16(A0, Wx30, g3);
            g0 = MFMA16(A1, Wx01, g0); g1 = MFMA16(A1, Wx11, g1);
            g2 = MFMA16(A1, Wx21, g2); g3 = MFMA16(A1, Wx31, g3);
            #pragma unroll
            for (int r = 0; r < 4; ++r) {
                const int tl = kg * 4 + r;        // C row = (lane>>4)*4 + reg
                float* d = &xacc[(tl * HID + hid) * 4];
                d[0] = g0[r]; d[1] = g1[r]; d[2] = g2[r]; d[3] = g3[r];
            }
        }
        BARRIER();
        // ---- 16 steady steps: h-recurrence only ----
        for (int s = 0; s < SC; s += 2) {
            {
                H_STEP_CORE(s, 0)
                if (kg == 0) {
                    h_lds[1][hid] = (_Float16)hv;
                    y0p[(size_t)(sc + s) * (BATCH * HID)] = (_Float16)hv;
                }
                BARRIER();
            }
            {
                H_STEP_CORE(s + 1, 1)
                if (kg == 0) {
                    h_lds[0][hid] = (_Float16)hv;
                    y0p[(size_t)(sc + s + 1) * (BATCH * HID)] = (_Float16)hv;
                }
                BARRIER();
            }
        }
    }
    if (kg == 0) {
        cstate[(size_t)b * HID + hid] = cc;
        hstate[(size_t)b * HID + hid] = hv;
    }
}

// ===================== Layer 1 =====================
// Same structure; A of the GEMM phase comes from the f16 y0 slab; Wy is
// reloaded from global each sub-chunk (L2-resident) to stay in register budget.
__global__ void __attribute__((amdgpu_flat_work_group_size(512, 512), amdgpu_waves_per_eu(2, 2)))
lstm_l1(const _Float16* __restrict__ y0in,
        const float* __restrict__ Wih, const float* __restrict__ Whh,
        const float* __restrict__ bih, const float* __restrict__ bhh,
        float* __restrict__ hstate, float* __restrict__ cstate,
        int t0, int t1)
{
    const int b    = blockIdx.x;
    const int tid  = threadIdx.x;
    const int lane = tid & 63;
    const int wave = tid >> 6;
    const int col  = lane & 15, kg = lane >> 4;
    const int hid  = wave * 16 + col;

    __shared__ __align__(16) float    xacc[SC * HID * 4];   // 32 KB (yacc)
    __shared__ __align__(16) _Float16 h_lds[2][HID];

    // ---- recurrent weights (AGPR-pinned, held) ----
    f16x8 Wh00 = LD8(Whh, 0 * HID + hid, HID, 0), Wh01 = LD8(Whh, 0 * HID + hid, HID, 1);
    f16x8 Wh02 = LD8(Whh, 0 * HID + hid, HID, 2), Wh03 = LD8(Whh, 0 * HID + hid, HID, 3);
    f16x8 Wh10 = LD8(Whh, 1 * HID + hid, HID, 0), Wh11 = LD8(Whh, 1 * HID + hid, HID, 1);
    f16x8 Wh12 = LD8(Whh, 1 * HID + hid, HID, 2), Wh13 = LD8(Whh, 1 * HID + hid, HID, 3);
    f16x8 Wh20 = LD8(Whh, 2 * HID + hid, HID, 0), Wh21 = LD8(Whh, 2 * HID + hid, HID, 1);
    f16x8 Wh22 = LD8(Whh, 2 * HID + hid, HID, 2), Wh23 = LD8(Whh, 2 * HID + hid, HID, 3);
    f16x8 Wh30 = LD8(Whh, 3 * HID + hid, HID, 0), Wh31 = LD8(Whh, 3 * HID + hid, HID, 1);
    f16x8 Wh32 = LD8(Whh, 3 * HID + hid, HID, 2), Wh33 = LD8(Whh, 3 * HID + hid, HID, 3);
    asm("" : "+a"(Wh00), "+a"(Wh01), "+a"(Wh02), "+a"(Wh03),
             "+a"(Wh10), "+a"(Wh11), "+a"(Wh12), "+a"(Wh13));
    asm("" : "+a"(Wh20), "+a"(Wh21), "+a"(Wh22), "+a"(Wh23),
             "+a"(Wh30), "+a"(Wh31), "+a"(Wh32), "+a"(Wh33));

    const float bs0 = bih[0 * HID + hid] + bhh[0 * HID + hid];
    const float bs1 = bih[1 * HID + hid] + bhh[1 * HID + hid];
    const float bs2 = bih[2 * HID + hid] + bhh[2 * HID + hid];
    const float bs3 = bih[3 * HID + hid] + bhh[3 * HID + hid];

    float cc = cstate[(size_t)b * HID + hid];
    float hv = hstate[(size_t)b * HID + hid];
    if (kg == 0) h_lds[0][hid] = (_Float16)hv;

    // GEMM A-load base: lane reads y0[rel=sc+col][b][kg*8 + j]
    const _Float16* yA = y0in + ((size_t)col * BATCH + b) * HID + kg * 8;

    const int nt = t1 - t0;
    for (int sc = 0; sc < nt; sc += SC) {
        // ---- GEMM phase: yacc = bias + y0·Wy (Wy reloaded, transient regs) ----
        {
            f16x8 Wy00 = LD8(Wih, 0 * HID + hid, HID, 0), Wy01 = LD8(Wih, 0 * HID + hid, HID, 1);
            f16x8 Wy02 = LD8(Wih, 0 * HID + hid, HID, 2), Wy03 = LD8(Wih, 0 * HID + hid, HID, 3);
            f16x8 Wy10 = LD8(Wih, 1 * HID + hid, HID, 0), Wy11 = LD8(Wih, 1 * HID + hid, HID, 1);
            f16x8 Wy12 = LD8(Wih, 1 * HID + hid, HID, 2), Wy13 = LD8(Wih, 1 * HID + hid, HID, 3);
            f16x8 Wy20 = LD8(Wih, 2 * HID + hid, HID, 0), Wy21 = LD8(Wih, 2 * HID + hid, HID, 1);
            f16x8 Wy22 = LD8(Wih, 2 * HID + hid, HID, 2), Wy23 = LD8(Wih, 2 * HID + hid, HID, 3);
            f16x8 Wy30 = LD8(Wih, 3 * HID + hid, HID, 0), Wy31 = LD8(Wih, 3 * HID + hid, HID, 1);
            f16x8 Wy32 = LD8(Wih, 3 * HID + hid, HID, 2), Wy33 = LD8(Wih, 3 * HID + hid, HID, 3);
            const _Float16* pa = yA + (size_t)sc * (BATCH * HID);
            f16x8 A0 = *(const f16x8*)(pa);
            f16x8 A1 = *(const f16x8*)(pa + 32);
            f16x8 A2 = *(const f16x8*)(pa + 64);
            f16x8 A3 = *(const f16x8*)(pa + 96);
            f32x4 g0 = splat4(bs0), g1 = splat4(bs1), g2 = splat4(bs2), g3 = splat4(bs3);
            g0 = MFMA16(A0, Wy00, g0); g1 = MFMA16(A0, Wy10, g1);
            g2 = MFMA16(A0, Wy20, g2); g3 = MFMA16(A0, Wy30, g3);
            g0 = MFMA16(A1, Wy01, g0); g1 = MFMA16(A1, Wy11, g1);
            g2 = MFMA16(A1, Wy21, g2); g3 = MFMA16(A1, Wy31, g3);
            g0 = MFMA16(A2, Wy02, g0); g1 = MFMA16(A2, Wy12, g1);
            g2 = MFMA16(A2, Wy22, g2); g3 = MFMA16(A2, Wy32, g3);
            g0 = MFMA16(A3, Wy03, g0); g1 = MFMA16(A3, Wy13, g1);
            g2 = MFMA16(A3, Wy23, g2); g3 = MFMA16(A3, Wy33, g3);
            #pragma unroll
            for (int r = 0; r < 4; ++r) {
                const int tl = kg * 4 + r;
                float* d = &xacc[(tl * HID + hid) * 4];
                d[0] = g0[r]; d[1] = g1[r]; d[2] = g2[r]; d[3] = g3[r];
            }
        }
        BARRIER();
        // ---- 16 steady steps ----
        for (int s = 0; s < SC; s += 2) {
            {
                H_STEP_CORE(s, 0)
                if (kg == 0) h_lds[1][hid] = (_Float16)hv;
                BARRIER();
            }
            {
                H_STEP_CORE(s + 1, 1)
                if (kg == 0) h_lds[0][hid] = (_Float16)hv;
                BARRIER();
            }
        }
    }
    if (kg == 0) {
        cstate[(size_t)b * HID + hid] = cc;
        hstate[(size_t)b * HID + hid] = hv;   // final h1 (fc reads this)
    }
}

// ===================== Final FC =====================
__global__ __launch_bounds__(128) void fc_kernel(
    const float* __restrict__ h1, const float* __restrict__ Wfc,
    const float* __restrict__ bfc, float* __restrict__ out)
{
    const int b = blockIdx.x;
    const int o = threadIdx.x;
    __shared__ float hs[HID];
    hs[o] = h1[(size_t)b * HID + o];
    __syncthreads();
    if (o < NOUT) {
        const float4* w  = reinterpret_cast<const float4*>(Wfc + (size_t)o * HID);
        const float4* hv = reinterpret_cast<const float4*>(hs);
        float acc = bfc[o];
        #pragma unroll
        for (int q = 0; q < HID / 4; ++q) {
            float4 wv = w[q]; float4 h4 = hv[q];
            acc = fmaf(wv.x, h4.x, fmaf(wv.y, h4.y, fmaf(wv.z, h4.z, fmaf(wv.w, h4.w, acc))));
        }
        out[(size_t)b * NOUT + o] = acc;
    }
}

extern "C" void kernel_launch(void* const* d_in, const int* in_sizes, int n_in,
                              void* d_out, int out_size, void* d_ws, size_t ws_size,
                              hipStream_t stream) {
    const float* x    = (const float*)d_in[0];
    const float* Wih0 = (const float*)d_in[1];
    const float* Whh0 = (const float*)d_in[2];
    const float* bih0 = (const float*)d_in[3];
    const float* bhh0 = (const float*)d_in[4];
    const float* Wih1 = (const float*)d_in[5];
    const float* Whh1 = (const float*)d_in[6];
    const float* bih1 = (const float*)d_in[7];
    const float* bhh1 = (const float*)d_in[8];
    const float* Wfc  = (const float*)d_in[9];
    const float* bfc  = (const float*)d_in[10];
    float* out = (float*)d_out;

    // ws: hst0 | cst0 | hst1 | cst1 (f32, 128KB each) then y0 slab (f16)
    float* hst0 = (float*)d_ws;
    float* cst0 = hst0 + BATCH * HID;
    float* hst1 = cst0 + BATCH * HID;
    float* cst1 = hst1 + BATCH * HID;
    _Float16* y0 = (_Float16*)(cst1 + BATCH * HID);

    const size_t stateBytes = (size_t)4 * BATCH * HID * sizeof(float);   // 512 KB
    size_t avail = ws_size > stateBytes ? ws_size - stateBytes : 0;
    int Tc = (int)(avail / ((size_t)BATCH * HID * 2));
    if (Tc > TLEN) Tc = TLEN;
    Tc &= ~(SC - 1);                  // sub-chunk multiple
    if (Tc < SC) Tc = SC;

    hipMemsetAsync(d_ws, 0, stateBytes, stream);

    for (int t0 = 0; t0 < TLEN; t0 += Tc) {
        int t1 = t0 + Tc; if (t1 > TLEN) t1 = TLEN;
        lstm_l0<<<BATCH, 512, 0, stream>>>(x, Wih0, Whh0, bih0, bhh0, hst0, cst0, y0, t0, t1);
        lstm_l1<<<BATCH, 512, 0, stream>>>(y0, Wih1, Whh1, bih1, bhh1, hst1, cst1, t0, t1);
    }
    fc_kernel<<<BATCH, 128, 0, stream>>>(hst1, Wfc, bfc, out);
}